// Round 1
// baseline (141.272 us; speedup 1.0000x reference)
//
#include <hip/hip_runtime.h>
#include <cstdint>
#include <cstddef>

#define BB 8
#define NN 48
#define DD 33
#define DP 64
#define HH 32
#define MM (NN*NN)        // 2304 rows (i,j)
#define NC (NN*HH)        // 1536 cols (k,h)
#define TM 18             // M tiles of 128
#define TN 12             // N tiles of 128
#define NBLK (TM*TN)      // 216 blocks per batch

typedef __attribute__((ext_vector_type(8))) _Float16 f16x8;
typedef __attribute__((ext_vector_type(4))) float f32x4;

// ---------------- Kernel 1: gather x = [embed | xfeat], compute s = mean_i x ----------
__global__ void k_setup(const int* __restrict__ xcat, const float* __restrict__ xfeat,
                        const float* __restrict__ embed, float* __restrict__ xw,
                        float* __restrict__ sw) {
    int b = blockIdx.x, t = threadIdx.x;
    for (int idx = t; idx < NN * DD; idx += 256) {
        int i = idx / DD, d = idx - i * DD;
        float v = (d < 32) ? embed[xcat[b * NN + i] * 32 + d] : xfeat[b * NN + i];
        xw[(b * NN + i) * DD + d] = v;
    }
    __syncthreads();
    if (t < DD) {
        float a = 0.f;
        for (int i = 0; i < NN; ++i) a += xw[(b * NN + i) * DD + t];
        sw[b * DD + t] = a * (1.0f / 48.0f);
    }
}

// ---------------- Kernel 2: build P[(i,j),d] and Dall[(k,h),d] in fp16 (K padded to 64)
__global__ void k_build_mats(const float* __restrict__ xw, const float* __restrict__ sw,
                             const float* __restrict__ coefs,
                             _Float16* __restrict__ Pw, _Float16* __restrict__ Dw) {
    int idx = blockIdx.x * 256 + threadIdx.x;
    if (idx < BB * MM * DP) {
        int d = idx & 63, rb = idx >> 6;
        int row = rb % MM, b = rb / MM;
        float v = 0.f;
        if (d < DD) {
            int i = row / NN, j = row - i * NN;
            v = xw[(b * NN + i) * DD + d] * xw[(b * NN + j) * DD + d];
        }
        Pw[idx] = (_Float16)v;
    } else {
        int id2 = idx - BB * MM * DP;
        int d = id2 & 63, nb = id2 >> 6;
        int n = nb % NC, b = nb / NC;
        float v = 0.f;
        if (d < DD) {
            int k = n >> 5, h = n & 31;
            float c0 = coefs[(d * 8 + 0) * HH + h];
            float c3 = coefs[(d * 8 + 3) * HH + h];
            v = c0 * xw[(b * NN + k) * DD + d] + c3 * sw[b * DD + d];
        }
        Dw[id2] = (_Float16)v;
    }
}

// ---------------- Kernel 3: E[b,k,i,h] and F[b,k,j,h] (F includes const + bias) ------
__global__ void k_build_ef(const float* __restrict__ xw, const float* __restrict__ sw,
                           const float* __restrict__ coefs, const float* __restrict__ eq_bias,
                           float* __restrict__ Ew, float* __restrict__ Fw) {
    int idx = blockIdx.x * 256 + threadIdx.x;
    const int HALF = BB * NN * NN * HH;  // 589824
    int which = idx >= HALF;
    int id2 = which ? idx - HALF : idx;
    int h = id2 & 31;
    int r = id2 >> 5;
    int ij = r % NN; r /= NN;
    int k = r % NN;  int b = r / NN;
    const float* xb = xw + b * NN * DD;
    const float* sb = sw + b * DD;
    const float* xk = xb + k * DD;
    const float* xi = xb + ij * DD;
    float a = 0.f;
    if (!which) {
        for (int d = 0; d < DD; ++d) {
            float c2 = coefs[(d * 8 + 2) * HH + h];
            float c6 = coefs[(d * 8 + 6) * HH + h];
            a += xi[d] * sb[d] * (c2 * xk[d] + c6 * sb[d]);
        }
        Ew[id2] = a;
    } else {
        for (int d = 0; d < DD; ++d) {
            float sd = sb[d], xkd = xk[d];
            float c1 = coefs[(d * 8 + 1) * HH + h];
            float c5 = coefs[(d * 8 + 5) * HH + h];
            float c4 = coefs[(d * 8 + 4) * HH + h];
            float c7 = coefs[(d * 8 + 7) * HH + h];
            a += sd * (xi[d] * (c1 * xkd + c5 * sd) + sd * (c4 * xkd + c7 * sd));
        }
        Fw[id2] = a + eq_bias[h];
    }
}

// ---------------- Kernel 4: MFMA GEMM + fused epilogue (relu + h-sum) ----------------
__global__ __launch_bounds__(256) void k_gemm(const _Float16* __restrict__ Pw,
                                              const _Float16* __restrict__ Dw,
                                              const float* __restrict__ Ew,
                                              const float* __restrict__ Fw,
                                              float* __restrict__ partials) {
    __shared__ __align__(16) _Float16 As[128][72];   // +8 pad breaks bank aliasing
    __shared__ __align__(16) _Float16 Bs[128][72];
    __shared__ float hacc[HH];
    int t = threadIdx.x;
    int bx = blockIdx.x, by = blockIdx.y, b = blockIdx.z;
    int M0 = by * 128, N0 = bx * 128;
    if (t < HH) hacc[t] = 0.f;

    const _Float16* Pg = Pw + ((size_t)b * MM + M0) * DP;
    const _Float16* Dg = Dw + ((size_t)b * NC + N0) * DP;
    for (int c = 0; c < 4; ++c) {
        int ch = c * 256 + t;
        int row = ch >> 3, col8 = (ch & 7) * 8;
        *(uint4*)&As[row][col8] = *(const uint4*)(Pg + row * DP + col8);
        *(uint4*)&Bs[row][col8] = *(const uint4*)(Dg + row * DP + col8);
    }
    __syncthreads();

    int lane = t & 63, wave = t >> 6;
    int wm = (wave >> 1) * 64, wn = (wave & 1) * 64;
    int lrow = lane & 15, quad = lane >> 4;

    f32x4 acc[4][4];
    for (int mt = 0; mt < 4; ++mt)
        for (int nt = 0; nt < 4; ++nt)
            acc[mt][nt] = (f32x4){0.f, 0.f, 0.f, 0.f};

    for (int ks = 0; ks < 2; ++ks) {
        f16x8 af[4], bf[4];
        for (int mt = 0; mt < 4; ++mt)
            af[mt] = *(const f16x8*)&As[wm + mt * 16 + lrow][ks * 32 + quad * 8];
        for (int nt = 0; nt < 4; ++nt)
            bf[nt] = *(const f16x8*)&Bs[wn + nt * 16 + lrow][ks * 32 + quad * 8];
        for (int mt = 0; mt < 4; ++mt)
            for (int nt = 0; nt < 4; ++nt)
                acc[mt][nt] = __builtin_amdgcn_mfma_f32_16x16x32_f16(af[mt], bf[nt], acc[mt][nt], 0, 0, 0);
    }

    // Epilogue: y = gemm + E[k,i,h] + F[k,j,h]; relu; accumulate per-h sums.
    float fsum[4] = {0.f, 0.f, 0.f, 0.f};
    const float* Eb[4];
    const float* Fb[4];
    int hh[4];
    for (int nt = 0; nt < 4; ++nt) {
        int ncol = N0 + wn + nt * 16 + lrow;   // lane's column: fixed (k,h)
        int k = ncol >> 5, h = ncol & 31;
        hh[nt] = h;
        size_t base = ((size_t)(b * NN + k) * NN) * HH + h;
        Eb[nt] = Ew + base;
        Fb[nt] = Fw + base;
    }
    for (int mt = 0; mt < 4; ++mt) {
        int rbase = M0 + wm + mt * 16 + quad * 4;
        for (int r = 0; r < 4; ++r) {
            int row = rbase + r;
            int i = row / NN, j = row - i * NN;
            for (int nt = 0; nt < 4; ++nt) {
                float y = acc[mt][nt][r] + Eb[nt][(size_t)i * HH] + Fb[nt][(size_t)j * HH];
                fsum[nt] += fmaxf(y, 0.f);
            }
        }
    }
    for (int nt = 0; nt < 4; ++nt) atomicAdd(&hacc[hh[nt]], fsum[nt]);
    __syncthreads();
    if (t < HH) {
        int blockLin = (b * TM + by) * TN + bx;
        partials[(size_t)blockLin * HH + t] = hacc[t];
    }
}

// ---------------- Kernel 5: final reduce -> relu(mean) @ out_w + out_b ---------------
__global__ void k_reduce(const float* __restrict__ partials, const float* __restrict__ out_w,
                         const float* __restrict__ out_b, float* __restrict__ out) {
    __shared__ float red[256];
    int b = blockIdx.x, t = threadIdx.x;
    int h = t & 31, g = t >> 5;
    float a = 0.f;
    for (int p = g; p < NBLK; p += 8) a += partials[(size_t)(b * NBLK + p) * HH + h];
    red[t] = a;
    __syncthreads();
    if (t < HH) {
        float tot = 0.f;
        for (int gg = 0; gg < 8; ++gg) tot += red[gg * 32 + t];
        float m = tot * (1.0f / 110592.0f);   // mean over 48^3
        red[t] = fmaxf(m, 0.f) * out_w[t];
    }
    __syncthreads();
    if (t == 0) {
        float o = 0.f;
        for (int h2 = 0; h2 < HH; ++h2) o += red[h2];
        out[b] = o + out_b[0];
    }
}

extern "C" void kernel_launch(void* const* d_in, const int* in_sizes, int n_in,
                              void* d_out, int out_size, void* d_ws, size_t ws_size,
                              hipStream_t stream) {
    (void)in_sizes; (void)n_in; (void)out_size; (void)ws_size;
    const int*   xcat    = (const int*)d_in[0];
    const float* xfeat   = (const float*)d_in[1];
    const float* embed   = (const float*)d_in[2];
    const float* coefs   = (const float*)d_in[3];
    const float* eq_bias = (const float*)d_in[4];
    const float* out_w   = (const float*)d_in[5];
    const float* out_b   = (const float*)d_in[6];
    float* out = (float*)d_out;

    // Workspace layout (256B-aligned segments), total ~8.9 MB
    char* w = (char*)d_ws;
    float*    xw       = (float*)(w + 0);         //  8*48*33 f32   = 50688 B
    float*    sw       = (float*)(w + 50688);     //  8*33 f32      (pad to 51968)
    _Float16* Pw       = (_Float16*)(w + 51968);  //  8*2304*64 f16 = 2359296 B
    _Float16* Dw       = (_Float16*)(w + 2411264);//  8*1536*64 f16 = 1572864 B
    float*    Ew       = (float*)(w + 3984128);   //  8*48*48*32 f32= 2359296 B
    float*    Fw       = (float*)(w + 6343424);   //  8*48*48*32 f32= 2359296 B
    float*    partials = (float*)(w + 8702720);   //  1728*32 f32   = 221184 B

    k_setup<<<dim3(BB), dim3(256), 0, stream>>>(xcat, xfeat, embed, xw, sw);
    k_build_mats<<<dim3(7680), dim3(256), 0, stream>>>(xw, sw, coefs, Pw, Dw);
    k_build_ef<<<dim3(4608), dim3(256), 0, stream>>>(xw, sw, coefs, eq_bias, Ew, Fw);
    k_gemm<<<dim3(TN, TM, BB), dim3(256), 0, stream>>>(Pw, Dw, Ew, Fw, partials);
    k_reduce<<<dim3(BB), dim3(256), 0, stream>>>(partials, out_w, out_b, out);
}

// Round 2
// 125.797 us; speedup vs baseline: 1.1230x; 1.1230x over previous
//
#include <hip/hip_runtime.h>
#include <cstdint>
#include <cstddef>

#define BB 8
#define NN 48
#define DD 33
#define KP 128           // padded merged-K dimension
#define HH 32
#define MM (NN*NN)       // 2304 rows (i,j)
#define NC (NN*HH)       // 1536 cols (k,h)
#define TILE 96
#define TM (MM/TILE)     // 24
#define TN (NC/TILE)     // 16
#define LDK 136          // LDS row stride in f16 (+8 pad -> conflict-free b128 reads)

typedef __attribute__((ext_vector_type(8))) _Float16 f16x8;
typedef __attribute__((ext_vector_type(4))) float f32x4;

// ---- Kernel A: gather x=[embed|xfeat], s = mean_i x, zero hsum --------------------
__global__ void k_setup(const int* __restrict__ xcat, const float* __restrict__ xfeat,
                        const float* __restrict__ embed, float* __restrict__ xw,
                        float* __restrict__ sw, float* __restrict__ hsum) {
    int b = blockIdx.x, t = threadIdx.x;
    for (int idx = t; idx < NN * DD; idx += 256) {
        int i = idx / DD, d = idx - i * DD;
        float v = (d < 32) ? embed[xcat[b * NN + i] * 32 + d] : xfeat[b * NN + i];
        xw[b * NN * DD + idx] = v;
    }
    if (t < HH) hsum[b * HH + t] = 0.f;
    __syncthreads();
    if (t < DD) {
        float a = 0.f;
        for (int i = 0; i < NN; ++i) a += xw[b * NN * DD + i * DD + t];
        sw[b * DD + t] = a * (1.0f / 48.0f);
    }
}

// ---- Kernel B: build P'[(i,j),128] and D'[(k,h),128] fp16 (E/F folded into K) ------
__global__ void k_build(const float* __restrict__ xw, const float* __restrict__ sw,
                        const float* __restrict__ coefs, const float* __restrict__ eq_bias,
                        _Float16* __restrict__ Pw, _Float16* __restrict__ Dw) {
    int idx = blockIdx.x * 256 + threadIdx.x;
    int rb = idx >> 4, chunk = idx & 15, d0 = chunk * 8;
    if (rb < BB * MM) {
        int b = rb / MM, row = rb % MM;
        int i = row / NN, j = row - i * NN;
        const float* xi = xw + (b * NN + i) * DD;
        const float* xj = xw + (b * NN + j) * DD;
        const float* sb = sw + b * DD;
        f16x8 v;
        for (int e = 0; e < 8; ++e) {
            int dp = d0 + e; float r = 0.f;
            if (dp < 33)                    r = xi[dp] * xj[dp];
            else if (dp >= 40 && dp < 73)   r = xi[dp - 40] * sb[dp - 40];
            else if (dp >= 80 && dp < 113)  r = xj[dp - 80] * sb[dp - 80];
            else if (dp == 120)             r = 1.f;
            v[e] = (_Float16)r;
        }
        *(f16x8*)&Pw[(size_t)rb * KP + d0] = v;
    } else {
        int rb2 = rb - BB * MM;
        int b = rb2 / NC, n = rb2 % NC;
        int k = n >> 5, h = n & 31;
        const float* xk = xw + (b * NN + k) * DD;
        const float* sb = sw + b * DD;
        f16x8 v;
        for (int e = 0; e < 8; ++e) {
            int dp = d0 + e; float r = 0.f;
            if (dp < 33) {
                int d = dp;
                r = coefs[(d * 8 + 0) * HH + h] * xk[d] + coefs[(d * 8 + 3) * HH + h] * sb[d];
            } else if (dp >= 40 && dp < 73) {
                int d = dp - 40;
                r = coefs[(d * 8 + 2) * HH + h] * xk[d] + coefs[(d * 8 + 6) * HH + h] * sb[d];
            } else if (dp >= 80 && dp < 113) {
                int d = dp - 80;
                r = coefs[(d * 8 + 1) * HH + h] * xk[d] + coefs[(d * 8 + 5) * HH + h] * sb[d];
            } else if (dp == 120) {
                float g = 0.f;
                for (int d = 0; d < DD; ++d) {
                    float sd = sb[d];
                    g += sd * sd * (coefs[(d * 8 + 4) * HH + h] * xk[d]
                                  + coefs[(d * 8 + 7) * HH + h] * sd);
                }
                r = g + eq_bias[h];
            }
            v[e] = (_Float16)r;
        }
        *(f16x8*)&Dw[(size_t)rb2 * KP + d0] = v;
    }
}

// ---- Kernel C: 96x96 MFMA GEMM (K=128) + fused relu + per-h sum -------------------
__global__ __launch_bounds__(256) void k_gemm(const _Float16* __restrict__ Pw,
                                              const _Float16* __restrict__ Dw,
                                              float* __restrict__ hsum) {
    __shared__ __align__(16) _Float16 As[TILE][LDK];
    __shared__ __align__(16) _Float16 Bs[TILE][LDK];
    __shared__ float hacc[HH];
    int t = threadIdx.x;
    int bx = blockIdx.x, by = blockIdx.y, b = blockIdx.z;
    int M0 = by * TILE, N0 = bx * TILE;
    if (t < HH) hacc[t] = 0.f;

    const _Float16* Pg = Pw + ((size_t)b * MM + M0) * KP;
    const _Float16* Dg = Dw + ((size_t)b * NC + N0) * KP;
    for (int c = 0; c < 6; ++c) {
        int ch = c * 256 + t;
        int row = ch >> 4, col = (ch & 15) * 8;
        *(f16x8*)&As[row][col] = *(const f16x8*)(Pg + row * KP + col);
        *(f16x8*)&Bs[row][col] = *(const f16x8*)(Dg + row * KP + col);
    }
    __syncthreads();

    int lane = t & 63, wave = t >> 6;
    int wm = (wave >> 1) * 48, wn = (wave & 1) * 48;
    int lrow = lane & 15, quad = lane >> 4;

    f32x4 acc[3][3];
    for (int mt = 0; mt < 3; ++mt)
        for (int nt = 0; nt < 3; ++nt)
            acc[mt][nt] = (f32x4){0.f, 0.f, 0.f, 0.f};

    for (int ks = 0; ks < 4; ++ks) {
        f16x8 af[3], bf[3];
        for (int mt = 0; mt < 3; ++mt)
            af[mt] = *(const f16x8*)&As[wm + mt * 16 + lrow][ks * 32 + quad * 8];
        for (int nt = 0; nt < 3; ++nt)
            bf[nt] = *(const f16x8*)&Bs[wn + nt * 16 + lrow][ks * 32 + quad * 8];
        for (int mt = 0; mt < 3; ++mt)
            for (int nt = 0; nt < 3; ++nt)
                acc[mt][nt] = __builtin_amdgcn_mfma_f32_16x16x32_f16(af[mt], bf[nt], acc[mt][nt], 0, 0, 0);
    }

    // Epilogue: y is complete (bias/E/F folded into GEMM). relu + per-h accumulate.
    float fs[3] = {0.f, 0.f, 0.f};
    for (int mt = 0; mt < 3; ++mt)
        for (int nt = 0; nt < 3; ++nt)
            for (int r = 0; r < 4; ++r)
                fs[nt] += fmaxf(acc[mt][nt][r], 0.f);
    for (int nt = 0; nt < 3; ++nt) {
        int h = (N0 + wn + nt * 16 + lrow) & 31;
        atomicAdd(&hacc[h], fs[nt]);
    }
    __syncthreads();
    if (t < HH) atomicAdd(&hsum[b * HH + t], hacc[t]);
}

// ---- Kernel D: out[b] = relu(hsum/48^3) @ out_w + out_b ---------------------------
__global__ void k_final(const float* __restrict__ hsum, const float* __restrict__ out_w,
                        const float* __restrict__ out_b, float* __restrict__ out) {
    __shared__ float red[BB * HH];
    int t = threadIdx.x;
    int h = t & 31;
    red[t] = fmaxf(hsum[t] * (1.0f / 110592.0f), 0.f) * out_w[h];
    __syncthreads();
    if (t < BB) {
        float a = 0.f;
        for (int x = 0; x < HH; ++x) a += red[t * HH + x];
        out[t] = a + out_b[0];
    }
}

extern "C" void kernel_launch(void* const* d_in, const int* in_sizes, int n_in,
                              void* d_out, int out_size, void* d_ws, size_t ws_size,
                              hipStream_t stream) {
    (void)in_sizes; (void)n_in; (void)out_size; (void)ws_size;
    const int*   xcat    = (const int*)d_in[0];
    const float* xfeat   = (const float*)d_in[1];
    const float* embed   = (const float*)d_in[2];
    const float* coefs   = (const float*)d_in[3];
    const float* eq_bias = (const float*)d_in[4];
    const float* out_w   = (const float*)d_in[5];
    const float* out_b   = (const float*)d_in[6];
    float* out = (float*)d_out;

    // Workspace layout (16B-aligned), total ~7.9 MB
    char* w = (char*)d_ws;
    float*    xw   = (float*)(w + 0);          // 8*48*33 f32 = 50688
    float*    sw   = (float*)(w + 51200);      // 8*33 f32
    float*    hsum = (float*)(w + 52480);      // 8*32 f32
    _Float16* Pw   = (_Float16*)(w + 53760);   // 8*2304*128 f16 = 4718592
    _Float16* Dw   = (_Float16*)(w + 4772352); // 8*1536*128 f16 = 3145728

    k_setup<<<dim3(BB), dim3(256), 0, stream>>>(xcat, xfeat, embed, xw, sw, hsum);
    k_build<<<dim3(1920), dim3(256), 0, stream>>>(xw, sw, coefs, eq_bias, Pw, Dw);
    k_gemm<<<dim3(TN, TM, BB), dim3(256), 0, stream>>>(Pw, Dw, hsum);
    k_final<<<dim3(1), dim3(256), 0, stream>>>(hsum, out_w, out_b, out);
}